// Round 8
// baseline (196.184 us; speedup 1.0000x reference)
//
#include <hip/hip_runtime.h>

// World model (established rounds 0-7): ALL inputs fp32, output buffer fp32.
// Fixed harness work (384 MB d_ws poison @ ~59 us + ~103 MB input restore +
// gaps) ~ 148 us of the total. R7: k1+k2 ~ 48 us, k2 ~ 40 vs ~16 us floor.
// This round: force 2 blocks/CU on k2 via __launch_bounds__(512,4) (VGPR<=128),
// preload mask/dir, full unroll -> deeper MLP at guaranteed occupancy.

#define B_ 4
#define N_ 128
#define D_ 128

typedef __attribute__((ext_vector_type(4))) float float4v;

// Static scratch: x = Dense2(GLU(Dense1(RMSNorm(q)))) as (B,N,3D) fp32.
// Fully rewritten by k1 every call before k2 reads it (stream-ordered).
__device__ __align__(16) float g_x[B_ * N_ * 3 * D_];

__device__ __forceinline__ float sigm(float x) { return 1.0f / (1.0f + __expf(-x)); }

// ---------------- Kernel 1: RMSNorm + GLU MLP -> g_x ----------------------------
// one block (256 threads) per (b,n) row; weights (~300 KB fp32) are L2-resident.
// Verbatim from the round-6/7 PASSING builds.
__global__ __launch_bounds__(256) void k1_mlp(
        const float* __restrict__ q, const float* __restrict__ norm_w,
        const float* __restrict__ W1, const float* __restrict__ b1,
        const float* __restrict__ W2, const float* __restrict__ b2) {
    const int row = blockIdx.x;   // 0 .. B*N-1
    const int t   = threadIdx.x;  // 0 .. 255

    __shared__ __align__(16) float hbuf[D_];
    __shared__ __align__(16) float h2buf[D_];
    __shared__ float ybuf[2 * D_];
    __shared__ float red4[4];

    // RMSNorm
    float v  = (t < D_) ? q[(size_t)row * D_ + t] : 0.0f;
    float ss = v * v;
    #pragma unroll
    for (int off = 32; off > 0; off >>= 1) ss += __shfl_down(ss, off);
    if ((t & 63) == 0) red4[t >> 6] = ss;
    __syncthreads();
    float var   = (red4[0] + red4[1] + red4[2] + red4[3]) * (1.0f / D_);
    float scale = rsqrtf(var + 1e-6f);
    if (t < D_) hbuf[t] = v * scale * (1.0f + norm_w[t]);
    __syncthreads();

    // matvec1: col t (0..255); y = h . W1[t,:] + b1[t]
    float y = b1[t];
    const float4v* wr = (const float4v*)(W1 + (size_t)t * D_);
    #pragma unroll 8
    for (int c = 0; c < D_ / 4; ++c) {
        float4v w4 = wr[c];
        float4v h4 = *(const float4v*)&hbuf[4 * c];
        y += w4.x * h4.x + w4.y * h4.y + w4.z * h4.z + w4.w * h4.w;
    }
    ybuf[t] = y;
    __syncthreads();
    if (t < D_) {
        float a = ybuf[t], g = ybuf[D_ + t];
        h2buf[t] = a * sigm(a) * sigm(g);    // silu(a) * sigmoid(g)
    }
    __syncthreads();

    // matvec2: col t (0..255); threads 0..127 also col 256+t
    float x0 = b2[t];
    float x1 = (t < D_) ? b2[2 * D_ + t] : 0.0f;
    const float4v* w0 = (const float4v*)(W2 + (size_t)t * D_);
    const float4v* w1 = (const float4v*)(W2 + (size_t)(2 * D_ + (t & (D_ - 1))) * D_); // clamped; deref only when t<D_
    #pragma unroll 8
    for (int c = 0; c < D_ / 4; ++c) {
        float4v h4 = *(const float4v*)&h2buf[4 * c];
        float4v a4 = w0[c];
        x0 += a4.x * h4.x + a4.y * h4.y + a4.z * h4.z + a4.w * h4.w;
        if (t < D_) {
            float4v b4 = w1[c];
            x1 += b4.x * h4.x + b4.y * h4.y + b4.z * h4.z + b4.w * h4.w;
        }
    }
    float* xr = g_x + (size_t)row * (3 * D_);
    xr[t] = x0;
    if (t < D_) xr[2 * D_ + t] = x1;
}

// ---------------- Kernel 2: pairwise reduce over j, fused residual epilogue ------
// one block per (b,i): 512 threads = 16 j-slots x 32 channel-quads; float4 loads.
// vs round 7: __launch_bounds__(512,4) guarantees 2 blocks/CU (16 waves/CU,
// VGPR<=128); mask/dir preloaded; j-loop fully unrolled so the scheduler can
// size the in-flight load window to the register budget.
__global__ __launch_bounds__(512, 4) void k2_pair(
        const float* __restrict__ q, const float* __restrict__ mu,
        const float* __restrict__ Wij, const float* __restrict__ dir,
        const float* __restrict__ mask, float* __restrict__ out) {
    const int blk  = blockIdx.x;       // b*N + i
    const int t    = threadIdx.x;      // 0..511
    const int quad = t & 31;           // channels 4*quad .. 4*quad+3
    const int js   = t >> 5;           // j-slot 0..15
    const int b    = blk >> 7;

    const float* Wb  = Wij  + (size_t)blk * (N_ * 3 * D_);
    const float* mb  = mask + (size_t)blk * N_;
    const float* db  = dir  + (size_t)blk * (N_ * 3);
    const float* mub = mu   + (size_t)b * (N_ * 3 * D_);
    const float* xb  = g_x  + (size_t)b * (N_ * 3 * D_);

    // preload mask & dir for all 8 j's of this thread (independent L2 loads)
    float mv[8], e0v[8], e1v[8], e2v[8];
    #pragma unroll
    for (int it = 0; it < 8; ++it) {
        const int j = it * 16 + js;
        mv[it]  = mb[j];
        e0v[it] = db[3 * j + 0];
        e1v[it] = db[3 * j + 1];
        e2v[it] = db[3 * j + 2];
    }

    float4v aq = {0.f, 0.f, 0.f, 0.f};
    float4v a0 = {0.f, 0.f, 0.f, 0.f};
    float4v a1 = {0.f, 0.f, 0.f, 0.f};
    float4v a2 = {0.f, 0.f, 0.f, 0.f};

    #pragma unroll
    for (int it = 0; it < 8; ++it) {
        const int j = it * 16 + js;
        const float m  = mv[it];
        const float e0 = e0v[it];
        const float e1 = e1v[it];
        const float e2 = e2v[it];

        const size_t base = (size_t)j * (3 * D_) + 4 * quad;
        float4v wq = __builtin_nontemporal_load((const float4v*)(Wb + base));
        float4v wR = __builtin_nontemporal_load((const float4v*)(Wb + base + D_));
        float4v wm = __builtin_nontemporal_load((const float4v*)(Wb + base + 2 * D_));
        float4v xq = *(const float4v*)(xb + base);
        float4v xR = *(const float4v*)(xb + base + D_);
        float4v xm = *(const float4v*)(xb + base + 2 * D_);
        float4v u0 = *(const float4v*)(mub + base);
        float4v u1 = *(const float4v*)(mub + base + D_);
        float4v u2 = *(const float4v*)(mub + base + 2 * D_);

        #pragma unroll
        for (int i = 0; i < 4; ++i) {
            aq[i] += wq[i] * (xq[i] * m);
            float tR = wR[i] * (xR[i] * m);
            float tm = wm[i] * (xm[i] * m);
            a0[i] += tR * e0 + tm * u0[i];
            a1[i] += tR * e1 + tm * u1[i];
            a2[i] += tR * e2 + tm * u2[i];
        }
    }

    // lanes l and l+32 of a wave share `quad`, differ in j-slot: fold with shfl.
    #pragma unroll
    for (int i = 0; i < 4; ++i) {
        aq[i] += __shfl_down(aq[i], 32);
        a0[i] += __shfl_down(a0[i], 32);
        a1[i] += __shfl_down(a1[i], 32);
        a2[i] += __shfl_down(a2[i], 32);
    }

    __shared__ __align__(16) float ws[8][4][D_];   // [wave][quantity][channel], 16 KB
    const int w = t >> 6, l = t & 63;
    if (l < 32) {
        *(float4v*)&ws[w][0][4 * quad] = aq;
        *(float4v*)&ws[w][1][4 * quad] = a0;
        *(float4v*)&ws[w][2][4 * quad] = a1;
        *(float4v*)&ws[w][3][4 * quad] = a2;
    }
    __syncthreads();

    // epilogue: 512 outputs = 4 quantities x 128 channels, FP32 nt stores.
    const int comp = t >> 7;       // 0 = dq, 1..3 = dmu components
    const int ch   = t & 127;
    float s = 0.f;
    #pragma unroll
    for (int wv = 0; wv < 8; ++wv) s += ws[wv][comp][ch];

    if (comp == 0) {
        const size_t o = (size_t)blk * D_ + ch;
        __builtin_nontemporal_store(q[o] + s, out + o);
    } else {
        const size_t o = ((size_t)blk * 3 + (comp - 1)) * D_ + ch;
        __builtin_nontemporal_store(mu[o] + s, out + (size_t)(B_ * N_ * D_) + o);
    }
}

extern "C" void kernel_launch(void* const* d_in, const int* in_sizes, int n_in,
                              void* d_out, int out_size, void* d_ws, size_t ws_size,
                              hipStream_t stream) {
    const float* q     = (const float*)d_in[0];
    const float* mu    = (const float*)d_in[1];
    const float* Wij   = (const float*)d_in[2];
    const float* dir   = (const float*)d_in[3];
    const float* mask  = (const float*)d_in[4];
    const float* normw = (const float*)d_in[5];
    const float* W1    = (const float*)d_in[6];
    const float* b1    = (const float*)d_in[7];
    const float* W2    = (const float*)d_in[8];
    const float* b2    = (const float*)d_in[9];

    k1_mlp <<<B_ * N_, 256, 0, stream>>>(q, normw, W1, b1, W2, b2);
    k2_pair<<<B_ * N_, 512, 0, stream>>>(q, mu, Wij, dir, mask, (float*)d_out);
}